// Round 1
// baseline (675.122 us; speedup 1.0000x reference)
//
#include <hip/hip_runtime.h>

#define ANUM 5
#define EPS 1e-10f

// ---------------------------------------------------------------------------
// Precompute kernel: builds the 3 batch-independent Cayley matrices
//   Q = (I - Bm)^{-1} (I + Bm), Bm = L - L^T, L[i+1][c] = bias[i+c] (c<=i)
// plus normalized weights w_r, w_s and the scalar gate t, into d_ws:
//   ws[  0.. 63] = Qr   ws[ 64..127] = Qt   ws[128..191] = Qy
//   ws[192..196] = w_r  ws[197..201] = w_s  ws[202]      = t
// ---------------------------------------------------------------------------
__global__ void precompute_kernel(const float* __restrict__ kernel_r,
                                  const float* __restrict__ kernel_t,
                                  const float* __restrict__ kernel_phi,
                                  const float* __restrict__ kernel_s,
                                  const float* __restrict__ bias_r,
                                  const float* __restrict__ bias_t,
                                  const float* __restrict__ bias_y,
                                  float* __restrict__ ws) {
  int tid = threadIdx.x;
  if (tid < 3) {
    const float* bias = (tid == 0) ? bias_r : (tid == 1) ? bias_t : bias_y;
    float* qout = ws + tid * 64;

    float Bm[8][8];
#pragma unroll
    for (int i = 0; i < 8; ++i)
#pragma unroll
      for (int j = 0; j < 8; ++j) Bm[i][j] = 0.f;
#pragma unroll
    for (int i = 0; i < 7; ++i) {
#pragma unroll 8
      for (int c = 0; c < 7; ++c) {
        if (c <= i) {
          float v = bias[i + c];
          Bm[i + 1][c] = v;   // strictly lower
          Bm[c][i + 1] = -v;  // strictly upper
        }
      }
    }
    float A[8][8], C[8][8];
#pragma unroll
    for (int i = 0; i < 8; ++i)
#pragma unroll
      for (int j = 0; j < 8; ++j) {
        float id = (i == j) ? 1.f : 0.f;
        A[i][j] = id - Bm[i][j];
        C[i][j] = id + Bm[i][j];
      }
    // Gauss-Jordan (no pivoting: sym part of I-Bm is I, SPD => stable)
#pragma unroll
    for (int p = 0; p < 8; ++p) {
      float inv = 1.f / A[p][p];
#pragma unroll
      for (int j = 0; j < 8; ++j) { A[p][j] *= inv; C[p][j] *= inv; }
#pragma unroll
      for (int r = 0; r < 8; ++r) {
        if (r == p) continue;
        float f = A[r][p];
#pragma unroll
        for (int j = 0; j < 8; ++j) { A[r][j] -= f * A[p][j]; C[r][j] -= f * C[p][j]; }
      }
    }
#pragma unroll
    for (int i = 0; i < 8; ++i)
#pragma unroll
      for (int j = 0; j < 8; ++j) qout[i * 8 + j] = C[i][j];
  } else if (tid == 3) {
    float sr = 0.f, ss = 0.f;
#pragma unroll
    for (int a = 0; a < ANUM; ++a) sr += kernel_r[a] * kernel_r[a];
#pragma unroll
    for (int a = 0; a < ANUM; ++a) ws[192 + a] = kernel_r[a] * kernel_r[a] / (sr + EPS);
#pragma unroll
    for (int a = 0; a < ANUM; ++a) ss += kernel_s[a] * kernel_s[a];
#pragma unroll
    for (int a = 0; a < ANUM; ++a) ws[197 + a] = kernel_s[a] * kernel_s[a] / (ss + EPS);
    float kt2 = kernel_t[0] * kernel_t[0];
    float kp2 = kernel_phi[0] * kernel_phi[0];
    ws[202] = kt2 / (kt2 + kp2 + EPS);
  }
}

// ---------------------------------------------------------------------------
// Main kernel: one wave per batch element, lane = i*8+j of the 8x8 matrix.
// Congruence transform C = Q M Q^T via 2-stage LDS round trip:
//   stage A (lane i,j): V[i][j] = dot(M row i, Q row j)   -> stored transposed
//   stage B (lane i,j): C[i][j] = dot(V^T row j, Q row i)
// Double-buffered LDS => 2 __syncthreads per transform.
// ---------------------------------------------------------------------------
__device__ __forceinline__ float dot8(float4 a0, float4 a1, float4 b0, float4 b1) {
  return a0.x * b0.x + a0.y * b0.y + a0.z * b0.z + a0.w * b0.w +
         a1.x * b1.x + a1.y * b1.y + a1.z * b1.z + a1.w * b1.w;
}

__device__ __forceinline__ float xform(float m, float* bufA, float* bufB,
                                       int lane, int i, int j,
                                       float4 qi0, float4 qi1,
                                       float4 qj0, float4 qj1) {
  bufA[lane] = m;
  __syncthreads();
  float4 r0 = *(const float4*)(bufA + i * 8);
  float4 r1 = *(const float4*)(bufA + i * 8 + 4);
  float v = dot8(r0, r1, qj0, qj1);
  bufB[j * 8 + i] = v;  // transposed store
  __syncthreads();
  float4 c0 = *(const float4*)(bufB + j * 8);
  float4 c1 = *(const float4*)(bufB + j * 8 + 4);
  return dot8(c0, c1, qi0, qi1);
}

__launch_bounds__(256)
__global__ void spdsru_kernel(const float* __restrict__ x,
                              const float* __restrict__ states,
                              const float* __restrict__ ws,
                              float* __restrict__ out,        // B*64
                              float* __restrict__ out_state,  // B*320
                              int B, int ITER, int W) {
  __shared__ __align__(16) float lds[4][2][64];
  const int tid = threadIdx.x;
  const int lane = tid & 63;
  const int wv = tid >> 6;
  const int i = lane >> 3, j = lane & 7;
  float* bufA = lds[wv][0];
  float* bufB = lds[wv][1];

  // Q rows -> registers (amortized over ITER elements)
  const float4 Qri0 = *(const float4*)(ws + 0 + i * 8);
  const float4 Qri1 = *(const float4*)(ws + 0 + i * 8 + 4);
  const float4 Qrj0 = *(const float4*)(ws + 0 + j * 8);
  const float4 Qrj1 = *(const float4*)(ws + 0 + j * 8 + 4);
  const float4 Qti0 = *(const float4*)(ws + 64 + i * 8);
  const float4 Qti1 = *(const float4*)(ws + 64 + i * 8 + 4);
  const float4 Qtj0 = *(const float4*)(ws + 64 + j * 8);
  const float4 Qtj1 = *(const float4*)(ws + 64 + j * 8 + 4);
  const float4 Qyi0 = *(const float4*)(ws + 128 + i * 8);
  const float4 Qyi1 = *(const float4*)(ws + 128 + i * 8 + 4);
  const float4 Qyj0 = *(const float4*)(ws + 128 + j * 8);
  const float4 Qyj1 = *(const float4*)(ws + 128 + j * 8 + 4);
  const float wr0 = ws[192], wr1 = ws[193], wr2 = ws[194], wr3 = ws[195], wr4 = ws[196];
  const float ks0 = ws[197], ks1 = ws[198], ks2 = ws[199], ks3 = ws[200], ks4 = ws[201];
  const float tg = ws[202];

  const int wave = (blockIdx.x * 256 + tid) >> 6;

  for (int it = 0; it < ITER; ++it) {
    int b = wave + it * W;           // uniform per wave; ITER uniform per grid
    bool active = (b < B);
    float X = 0.f, M0 = 0.f, M1 = 0.f, M2 = 0.f, M3 = 0.f, M4 = 0.f;
    if (active) {
      const float* S = states + (size_t)b * 320;
      X = x[(size_t)b * 64 + lane];
      M0 = S[0 * 64 + lane];
      M1 = S[1 * 64 + lane];
      M2 = S[2 * 64 + lane];
      M3 = S[3 * 64 + lane];
      M4 = S[4 * 64 + lane];
    }
    // Yt = nus(M, w_r)
    float Yt = wr0 * M0 + wr1 * M1 + wr2 * M2 + wr3 * M3 + wr4 * M4;
    // Rt = Qr Yt Qr^T
    float Rt = xform(Yt, bufA, bufB, lane, i, j, Qri0, Qri1, Qrj0, Qrj1);
    // Tt = (1-t) X + t Rt
    float Tt = (1.f - tg) * X + tg * Rt;
    // Phit = Qt Tt Qt^T
    float Ph = xform(Tt, bufA, bufB, lane, i, j, Qti0, Qti1, Qtj0, Qtj1);
    // Mt = (1-alpha) Mt_1 + alpha Phit
    M0 = (1.0f - 0.01f) * M0 + 0.01f * Ph;
    M1 = (1.0f - 0.25f) * M1 + 0.25f * Ph;
    M2 = (1.0f - 0.5f)  * M2 + 0.5f  * Ph;
    M3 = (1.0f - 0.9f)  * M3 + 0.9f  * Ph;
    M4 = (1.0f - 0.99f) * M4 + 0.99f * Ph;
    // St = nus(Mt, w_s); Ot = Qy St Qy^T
    float St = ks0 * M0 + ks1 * M1 + ks2 * M2 + ks3 * M3 + ks4 * M4;
    float Ot = xform(St, bufA, bufB, lane, i, j, Qyi0, Qyi1, Qyj0, Qyj1);

    if (active) {
      out[(size_t)b * 64 + lane] = Ot;
      float* SO = out_state + (size_t)b * 320;
      SO[0 * 64 + lane] = M0;
      SO[1 * 64 + lane] = M1;
      SO[2 * 64 + lane] = M2;
      SO[3 * 64 + lane] = M3;
      SO[4 * 64 + lane] = M4;
    }
  }
}

extern "C" void kernel_launch(void* const* d_in, const int* in_sizes, int n_in,
                              void* d_out, int out_size, void* d_ws, size_t ws_size,
                              hipStream_t stream) {
  const float* x          = (const float*)d_in[0];
  const float* states     = (const float*)d_in[1];
  const float* kernel_r   = (const float*)d_in[2];
  const float* kernel_t   = (const float*)d_in[3];
  const float* kernel_phi = (const float*)d_in[4];
  const float* kernel_s   = (const float*)d_in[5];
  const float* bias_r     = (const float*)d_in[6];
  const float* bias_t     = (const float*)d_in[7];
  const float* bias_y     = (const float*)d_in[8];
  float* ws = (float*)d_ws;
  float* out = (float*)d_out;

  const int B = in_sizes[0] / 64;
  float* out_state = out + (size_t)B * 64;

  precompute_kernel<<<1, 64, 0, stream>>>(kernel_r, kernel_t, kernel_phi, kernel_s,
                                          bias_r, bias_t, bias_y, ws);

  const int blocks = 2048;           // 8192 waves; B=262144 -> 32 elements/wave
  const int W = blocks * 4;          // waves in grid
  const int ITER = (B + W - 1) / W;
  spdsru_kernel<<<blocks, 256, 0, stream>>>(x, states, ws, out, out_state, B, ITER, W);
}